// Round 17
// baseline (797.354 us; speedup 1.0000x reference)
//
#include <hip/hip_runtime.h>
#include <hip/hip_bf16.h>

typedef __attribute__((ext_vector_type(8))) short s16x8;
typedef __attribute__((ext_vector_type(4))) short s16x4;
typedef __attribute__((ext_vector_type(4))) float f32x4;

#define GAS __attribute__((address_space(1)))
#define LAS __attribute__((address_space(3)))

#define WAITV(N) asm volatile("s_waitcnt vmcnt(" #N ")" ::: "memory")
#define WAITL() asm volatile("s_waitcnt lgkmcnt(0)" ::: "memory")
#define BAR() __builtin_amdgcn_s_barrier()

__device__ __forceinline__ float b2f(unsigned short u) {
  union { unsigned int i; float f; } x; x.i = ((unsigned int)u) << 16; return x.f;
}
__device__ __forceinline__ unsigned short f2b(float f) {
  union { float f; unsigned int i; } x; x.f = f;
  unsigned int r = x.i + 0x7fffu + ((x.i >> 16) & 1u);
  return (unsigned short)(r >> 16);
}

// async global->LDS, 16B per lane; lds dest is wave-uniform base + lane*16
__device__ __forceinline__ void gl16(const unsigned short* g, unsigned short* l) {
  __builtin_amdgcn_global_load_lds((const GAS unsigned int*)g,
                                   (LAS unsigned int*)l, 16, 0, 0);
}

// ---------------- packing ----------------
__global__ __launch_bounds__(256) void pack_qkv_k(const float* __restrict__ wq,
                                                  const float* __restrict__ wk,
                                                  const float* __restrict__ wv,
                                                  unsigned short* __restrict__ dst) {
  int idx = blockIdx.x * 256 + threadIdx.x;   // n*512 + c
  int n = idx >> 9, c = idx & 511;
  int sel = n >> 9;
  int hn = n & 511;
  const float* src = sel == 0 ? wq : (sel == 1 ? wk : wv);
  float v = src[((hn >> 6) << 15) + (c << 6) + (hn & 63)];  // wq[h][c][d]
  dst[idx] = f2b(v);
}

// dst[n][k] = src[k][n], src is (K,N) row-major
__global__ __launch_bounds__(256) void pack_T_k(const float* __restrict__ src,
                                                unsigned short* __restrict__ dst,
                                                int K, int N) {
  int idx = blockIdx.x * 256 + threadIdx.x;
  int n = idx / K, k = idx % K;
  dst[idx] = f2b(src[(long long)k * N + n]);
}

// ---------------- LN1 fused with x->bf16 pack (fp32 input, writes h and xb) ----------------
__global__ __launch_bounds__(256) void ln_fx_k(const float* __restrict__ in,
                                               const float* __restrict__ g,
                                               const float* __restrict__ bb,
                                               unsigned short* __restrict__ out,
                                               unsigned short* __restrict__ xb) {
  int row = blockIdx.x * 4 + (threadIdx.x >> 6);
  int lane = threadIdx.x & 63;
  const float* p = in + (size_t)row * 512 + lane * 8;
  f32x4 a = *(const f32x4*)p;
  f32x4 b = *(const f32x4*)(p + 4);
  float vals[8] = {a.x, a.y, a.z, a.w, b.x, b.y, b.z, b.w};
  s16x8 xo;
#pragma unroll
  for (int i = 0; i < 8; i++) xo[i] = (short)f2b(vals[i]);
  *(s16x8*)(xb + (size_t)row * 512 + lane * 8) = xo;
  float s = 0.f, q = 0.f;
#pragma unroll
  for (int i = 0; i < 8; i++) { s += vals[i]; q += vals[i] * vals[i]; }
#pragma unroll
  for (int off = 1; off < 64; off <<= 1) {
    s += __shfl_xor(s, off);
    q += __shfl_xor(q, off);
  }
  float mean = s * (1.0f / 512.0f);
  float rstd = rsqrtf(q * (1.0f / 512.0f) - mean * mean + 1e-5f);
  const float* gp = g + lane * 8;
  const float* bp = bb + lane * 8;
  s16x8 o;
#pragma unroll
  for (int i = 0; i < 8; i++) o[i] = (short)f2b((vals[i] - mean) * rstd * gp[i] + bp[i]);
  *(s16x8*)(out + (size_t)row * 512 + lane * 8) = o;
}

// ---------------- layernorm (wave per row, C=512), fp32 input (fallback) ----------------
__global__ __launch_bounds__(256) void ln_k(const float* __restrict__ in,
                                            const float* __restrict__ g,
                                            const float* __restrict__ bb,
                                            unsigned short* __restrict__ out) {
  int row = blockIdx.x * 4 + (threadIdx.x >> 6);
  int lane = threadIdx.x & 63;
  const float* p = in + (size_t)row * 512 + lane * 8;
  f32x4 a = *(const f32x4*)p;
  f32x4 b = *(const f32x4*)(p + 4);
  float vals[8] = {a.x, a.y, a.z, a.w, b.x, b.y, b.z, b.w};
  float s = 0.f, q = 0.f;
#pragma unroll
  for (int i = 0; i < 8; i++) { s += vals[i]; q += vals[i] * vals[i]; }
#pragma unroll
  for (int off = 1; off < 64; off <<= 1) {
    s += __shfl_xor(s, off);
    q += __shfl_xor(q, off);
  }
  float mean = s * (1.0f / 512.0f);
  float rstd = rsqrtf(q * (1.0f / 512.0f) - mean * mean + 1e-5f);
  const float* gp = g + lane * 8;
  const float* bp = bb + lane * 8;
  s16x8 o;
#pragma unroll
  for (int i = 0; i < 8; i++) o[i] = (short)f2b((vals[i] - mean) * rstd * gp[i] + bp[i]);
  *(s16x8*)(out + (size_t)row * 512 + lane * 8) = o;
}

// ---------------- layernorm, bf16 input ----------------
__global__ __launch_bounds__(256) void ln_b_k(const unsigned short* __restrict__ in,
                                              const float* __restrict__ g,
                                              const float* __restrict__ bb,
                                              unsigned short* __restrict__ out) {
  int row = blockIdx.x * 4 + (threadIdx.x >> 6);
  int lane = threadIdx.x & 63;
  s16x8 v8 = *(const s16x8*)(in + (size_t)row * 512 + lane * 8);
  float vals[8];
#pragma unroll
  for (int i = 0; i < 8; i++) vals[i] = b2f((unsigned short)v8[i]);
  float s = 0.f, q = 0.f;
#pragma unroll
  for (int i = 0; i < 8; i++) { s += vals[i]; q += vals[i] * vals[i]; }
#pragma unroll
  for (int off = 1; off < 64; off <<= 1) {
    s += __shfl_xor(s, off);
    q += __shfl_xor(q, off);
  }
  float mean = s * (1.0f / 512.0f);
  float rstd = rsqrtf(q * (1.0f / 512.0f) - mean * mean + 1e-5f);
  const float* gp = g + lane * 8;
  const float* bp = bb + lane * 8;
  s16x8 o;
#pragma unroll
  for (int i = 0; i < 8; i++) o[i] = (short)f2b((vals[i] - mean) * rstd * gp[i] + bp[i]);
  *(s16x8*)(out + (size_t)row * 512 + lane * 8) = o;
}

// ---------------- attention (one wave per (b,h); T=16, D=64) ----------------
__global__ __launch_bounds__(256) void attn_k(const unsigned short* __restrict__ qkv,
                                              unsigned short* __restrict__ o) {
  int w = (blockIdx.x << 2) + (threadIdx.x >> 6);
  int lane = threadIdx.x & 63;
  int b = w >> 3, h = w & 7;
  int t = lane >> 2, p = lane & 3;   // 4 lanes per query row, 16 d's each

  size_t rowq = (size_t)(b * 16 + t) * 1536 + h * 64 + p * 16;
  float q[16];
  {
    s16x8 q0 = *(const s16x8*)(qkv + rowq);
    s16x8 q1 = *(const s16x8*)(qkv + rowq + 8);
#pragma unroll
    for (int i = 0; i < 8; i++) {
      q[i] = b2f((unsigned short)q0[i]) * 0.125f;
      q[8 + i] = b2f((unsigned short)q1[i]) * 0.125f;
    }
  }
  float lg[16];
  size_t kbase = (size_t)(b * 16) * 1536 + 512 + h * 64 + p * 16;
#pragma unroll
  for (int s = 0; s < 16; s++) {
    const unsigned short* kp = qkv + kbase + (size_t)s * 1536;
    s16x8 k0 = *(const s16x8*)kp;
    s16x8 k1 = *(const s16x8*)(kp + 8);
    float d = 0.f;
#pragma unroll
    for (int i = 0; i < 8; i++)
      d += q[i] * b2f((unsigned short)k0[i]) + q[8 + i] * b2f((unsigned short)k1[i]);
    d += __shfl_xor(d, 1);
    d += __shfl_xor(d, 2);
    lg[s] = d;
  }
  float mx = -1e30f;
#pragma unroll
  for (int s = 0; s < 16; s++)
    if (s <= t) mx = fmaxf(mx, lg[s]);
  float den = 0.f;
#pragma unroll
  for (int s = 0; s < 16; s++) {
    float e = (s <= t) ? __expf(lg[s] - mx) : 0.f;
    lg[s] = e;
    den += e;
  }
  float inv = 1.f / den;
  float acc[16] = {};
  size_t vbase = kbase + 512;
#pragma unroll
  for (int s = 0; s < 16; s++) {
    const unsigned short* vp = qkv + vbase + (size_t)s * 1536;
    s16x8 v0 = *(const s16x8*)vp;
    s16x8 v1 = *(const s16x8*)(vp + 8);
    float a = lg[s] * inv;
#pragma unroll
    for (int i = 0; i < 8; i++) {
      acc[i] += a * b2f((unsigned short)v0[i]);
      acc[8 + i] += a * b2f((unsigned short)v1[i]);
    }
  }
  size_t orow = (size_t)(b * 16 + t) * 512 + h * 64 + p * 16;
  s16x8 r0, r1;
#pragma unroll
  for (int i = 0; i < 8; i++) {
    r0[i] = (short)f2b(acc[i]);
    r1[i] = (short)f2b(acc[8 + i]);
  }
  *(s16x8*)(o + orow) = r0;
  *(s16x8*)(o + orow + 8) = r1;
}

// ------- bf16 MFMA GEMM: 256x256 tile, BK=32, 8 waves, 8-slot ring (64KB LDS) -------
// Residency experiment: 64KB LDS -> 2 blocks/CU; cross-block overlap fills
// barrier/latency gaps (m97/m114 mechanism). r16 cadence, shortened lead:
//   even(t): stage A(t+1) x2 | WAITV(2) (tile t landed, A(t+1) in flight) | BAR |
//            ds_read B + A m0-3 | setprio(1) 16 MFMA setprio(0)
//   odd(t):  ds_read A m4-7 | stage B(t+1) x2 | BAR | setprio(1) 16 MFMA setprio(0)
// Race-freedom: all stages target opposite-parity slots; tile t-1's readers all
// passed t-1's trailing (odd) BAR before tile t's phases begin. vmcnt never 0
// until the final tile. Source-side XOR swizzle (0 conflicts measured r2-r16).
enum { EPI_BF16 = 0, EPI_RESF32 = 1, EPI_RELU = 2, EPI_YBB = 3, EPI_OUTB = 4 };

template <int EPI>
__global__ __launch_bounds__(512) void gemm_bt(
    const unsigned short* __restrict__ A,   // (M, K) bf16
    const unsigned short* __restrict__ Bt,  // (N, K) bf16
    int K, int N, int nT,
    const float* __restrict__ bias, const void* __restrict__ res,
    float* __restrict__ outF, unsigned short* __restrict__ outB) {
  __shared__ __align__(16) unsigned char SM[65536];  // 8 x 8KB half-tile slots

  int tid = threadIdx.x;
  // XCD-chunked 1D swizzle, N-fastest tile order (grids are multiples of 8)
  int lid = ((int)blockIdx.x & 7) * ((int)gridDim.x >> 3) + ((int)blockIdx.x >> 3);
  int mBase = (lid / nT) * 256;
  int nBase = (lid % nT) * 256;

  int lane = tid & 63;
  int wid = tid >> 6;     // 0..7
  int wm = wid >> 2;      // 0..1 -> A half (rows wm*128..)
  int wn = wid & 3;       // 0..3 -> out cols wn*64..
  int l15 = lane & 15;
  int s4 = lane >> 4;
  int lr4 = s4 * 4;
  int fc = ((s4 ^ ((l15 >> 1) & 3)) << 3);   // swizzled 8-elem slot for ds_read

  // staging: thread covers row tid>>2 (0..127) of a half, 16B slot tid&3;
  // source col pre-swizzled: LDS[r][p] = G[r][p ^ ((r>>1)&3)]
  int srow = tid >> 2;
  int scol = (((tid & 3) ^ ((srow >> 1) & 3)) << 3);
  const unsigned short* pa = A + (size_t)(mBase + srow) * K + scol;
  const unsigned short* pb = Bt + (size_t)(nBase + srow) * K + scol;
  size_t k128 = (size_t)128 * K;
  unsigned short* dstB = (unsigned short*)SM + wid * 512;  // + slot*4096 shorts

  f32x4 acc[8][4] = {};

  auto stgA = [&](int slot, int a, int t) {   // A half a of tile t -> ring slot
    gl16(pa + (size_t)a * k128 + t * 32, dstB + slot * 4096);
  };
  auto stgB = [&](int slot, int b, int t) {
    gl16(pb + (size_t)b * k128 + t * 32, dstB + slot * 4096);
  };

  int NT = K >> 5;   // 16 or 64 here
  // prologue: full tile 0 into parity-0 slots
  stgA(0, 0, 0);  stgA(1, 1, 0);
  stgB(2, 0, 0);  stgB(3, 1, 0);

  for (int t = 0; t < NT; ++t) {
    int sb = (t & 1) << 2;
    int sn = ((t + 1) & 1) << 2;
    const unsigned short* hA = (const unsigned short*)SM + (size_t)(sb + wm) * 4096;
    const unsigned short* hB = (const unsigned short*)SM + (size_t)(sb + 2 + (wn >> 1)) * 4096;
    int br = (wn & 1) * 64;
    s16x8 af[4], bf[4];

    // ---------- even phase ----------
    if (t + 1 < NT) {
      stgA(sn + 0, 0, t + 1);
      stgA(sn + 1, 1, t + 1);
      WAITV(2);      // tile t's 4 landed; A(t+1) x2 in flight
    } else {
      WAITV(0);      // last tile
    }
    BAR();           // collective: all waves' shares of tile t landed
#pragma unroll
    for (int n = 0; n < 4; ++n)
      bf[n] = *(const s16x8*)&hB[(br + n * 16 + l15) * 32 + fc];
#pragma unroll
    for (int m = 0; m < 4; ++m)
      af[m] = *(const s16x8*)&hA[(m * 16 + l15) * 32 + fc];
    __builtin_amdgcn_s_setprio(1);
#pragma unroll
    for (int m = 0; m < 4; ++m)
#pragma unroll
      for (int n = 0; n < 4; ++n)
        acc[m][n] = __builtin_amdgcn_mfma_f32_16x16x32_bf16(af[m], bf[n], acc[m][n], 0, 0, 0);
    __builtin_amdgcn_s_setprio(0);

    // ---------- odd phase ----------
#pragma unroll
    for (int m = 0; m < 4; ++m)
      af[m] = *(const s16x8*)&hA[((m + 4) * 16 + l15) * 32 + fc];
    if (t + 1 < NT) {
      stgB(sn + 2, 0, t + 1);
      stgB(sn + 3, 1, t + 1);
    }
    BAR();           // end-of-tile: all reads of tile t done before its slots reused
    __builtin_amdgcn_s_setprio(1);
#pragma unroll
    for (int m = 0; m < 4; ++m)
#pragma unroll
      for (int n = 0; n < 4; ++n)
        acc[m + 4][n] = __builtin_amdgcn_mfma_f32_16x16x32_bf16(af[m], bf[n], acc[m + 4][n], 0, 0, 0);
    __builtin_amdgcn_s_setprio(0);
  }
  BAR();             // safe to reuse LDS for epilogue staging

  if (EPI == EPI_RESF32 || EPI == EPI_OUTB) {
    // fp32 output: direct stores are full 64B lines
#pragma unroll
    for (int n = 0; n < 4; n++) {
      int gc2 = nBase + wn * 64 + n * 16 + l15;
      float bv = bias[gc2];
#pragma unroll
      for (int m = 0; m < 8; m++) {
#pragma unroll
        for (int j = 0; j < 4; j++) {
          int gr = mBase + wm * 128 + m * 16 + lr4 + j;
          size_t off = (size_t)gr * N + gc2;
          float v = acc[m][n][j] + bv;
          if (EPI == EPI_RESF32)
            outF[off] = v + ((const float*)res)[off];
          else
            outF[off] = v + b2f(((const unsigned short*)res)[off]);
        }
      }
    }
  } else {
    // bf16 output: stage per-wave 16x64 fp32 in LDS, read back row-contiguous,
    // write short4 (16 lanes x 8B = 128B full-line runs per row)
    float* ep = (float*)SM + wid * 1088;   // 4352 B/wave, row stride 68 floats
    int colc = nBase + wn * 64 + l15 * 4;
    f32x4 bias4 = {0.f, 0.f, 0.f, 0.f};
    if (EPI != EPI_BF16) bias4 = *(const f32x4*)&bias[colc];
#pragma unroll
    for (int m = 0; m < 8; m++) {
#pragma unroll
      for (int n = 0; n < 4; n++)
#pragma unroll
        for (int j = 0; j < 4; j++)
          ep[(lr4 + j) * 68 + n * 16 + l15] = acc[m][n][j];
      WAITL();
#pragma unroll
      for (int rd = 0; rd < 4; rd++) {
        int r = s4 + 4 * rd;
        f32x4 v = *(const f32x4*)&ep[r * 68 + l15 * 4];
        v.x += bias4.x; v.y += bias4.y; v.z += bias4.z; v.w += bias4.w;
        int gr = mBase + wm * 128 + m * 16 + r;
        size_t off = (size_t)gr * N + colc;
        if (EPI == EPI_YBB) {
          s16x4 rb = *(const s16x4*)((const unsigned short*)res + off);
          v.x += b2f((unsigned short)rb[0]); v.y += b2f((unsigned short)rb[1]);
          v.z += b2f((unsigned short)rb[2]); v.w += b2f((unsigned short)rb[3]);
        } else if (EPI == EPI_RELU) {
          v.x = fmaxf(v.x, 0.f); v.y = fmaxf(v.y, 0.f);
          v.z = fmaxf(v.z, 0.f); v.w = fmaxf(v.w, 0.f);
        }
        s16x4 o;
        o[0] = (short)f2b(v.x); o[1] = (short)f2b(v.y);
        o[2] = (short)f2b(v.z); o[3] = (short)f2b(v.w);
        *(s16x4*)(outB + off) = o;
      }
      WAITL();  // reads of m done before m+1 overwrites (per-wave region)
    }
  }
}

// ---------------- launch ----------------
extern "C" void kernel_launch(void* const* d_in, const int* in_sizes, int n_in,
                              void* d_out, int out_size, void* d_ws, size_t ws_size,
                              hipStream_t stream) {
  const float* x      = (const float*)d_in[0];
  const float* ln1_g  = (const float*)d_in[1];
  const float* ln1_b  = (const float*)d_in[2];
  const float* wq     = (const float*)d_in[3];
  const float* wk     = (const float*)d_in[4];
  const float* wv     = (const float*)d_in[5];
  const float* w_proj = (const float*)d_in[6];
  const float* b_proj = (const float*)d_in[7];
  const float* ln2_g  = (const float*)d_in[8];
  const float* ln2_b  = (const float*)d_in[9];
  const float* w1     = (const float*)d_in[10];
  const float* b1     = (const float*)d_in[11];
  const float* w2     = (const float*)d_in[12];
  const float* b2     = (const float*)d_in[13];
  float* out = (float*)d_out;

  char* ws = (char*)d_ws;
  unsigned short* qkvT  = (unsigned short*)(ws + 0);          // 1.5 MB
  unsigned short* projT = (unsigned short*)(ws + 1572864);    // 0.5 MB
  unsigned short* w1T   = (unsigned short*)(ws + 2097152);    // 2 MB
  unsigned short* w2T   = (unsigned short*)(ws + 4194304);    // 2 MB
  unsigned short* hbuf  = (unsigned short*)(ws + 6291456);    // 67 MB (h, then h2)
  unsigned short* qkv   = (unsigned short*)(ws + 73400320);   // 201 MB of 268 MB region (ff)
  unsigned short* xb    = (unsigned short*)(ws + 274726912);  // 67 MB spare in ff region
  unsigned short* obuf  = (unsigned short*)(ws + 341835776);  // 67 MB
  unsigned short* ybuf  = (unsigned short*)(ws + 408944640);  // 67 MB (bf16 y) if room
  bool yb16 = ws_size >= 476053504ull;

  pack_qkv_k<<<3072, 256, 0, stream>>>(wq, wk, wv, qkvT);
  pack_T_k<<<1024, 256, 0, stream>>>(w_proj, projT, 512, 512);
  pack_T_k<<<4096, 256, 0, stream>>>(w1, w1T, 512, 2048);
  pack_T_k<<<4096, 256, 0, stream>>>(w2, w2T, 2048, 512);

  unsigned short* ff = qkv;  // ff (268 MB) overlays qkv+xb after both are dead
  if (yb16) {
    // LN1 fused with x->bf16 pack (reads x once)
    ln_fx_k<<<16384, 256, 0, stream>>>(x, ln1_g, ln1_b, hbuf, xb);
    // qkv = h @ [wq|wk|wv]  (M=65536, K=512, N=1536): 256 m x 6 n = 1536
    gemm_bt<EPI_BF16><<<1536, 512, 0, stream>>>(hbuf, qkvT, 512, 1536, 6,
                                                nullptr, nullptr, nullptr, qkv);
    attn_k<<<8192, 256, 0, stream>>>(qkv, obuf);
    // y(bf16) = o @ w_proj + b_proj + xb
    gemm_bt<EPI_YBB><<<512, 512, 0, stream>>>(obuf, projT, 512, 512, 2,
                                              b_proj, xb, nullptr, ybuf);
    ln_b_k<<<16384, 256, 0, stream>>>(ybuf, ln2_g, ln2_b, hbuf);
    // ff = relu(h2 @ w1 + b1)  — overwrites qkv AND xb region (both dead)
    gemm_bt<EPI_RELU><<<2048, 512, 0, stream>>>(hbuf, w1T, 512, 2048, 8,
                                                b1, nullptr, nullptr, ff);
    // out(f32) = ff @ w2 + b2 + y(bf16)
    gemm_bt<EPI_OUTB><<<512, 512, 0, stream>>>(ff, w2T, 2048, 512, 2,
                                               b2, ybuf, out, nullptr);
  } else {
    // fallback: y fp32 in d_out, no xb
    ln_k<<<16384, 256, 0, stream>>>(x, ln1_g, ln1_b, hbuf);
    gemm_bt<EPI_BF16><<<1536, 512, 0, stream>>>(hbuf, qkvT, 512, 1536, 6,
                                                nullptr, nullptr, nullptr, qkv);
    attn_k<<<8192, 256, 0, stream>>>(qkv, obuf);
    gemm_bt<EPI_RESF32><<<512, 512, 0, stream>>>(obuf, projT, 512, 512, 2,
                                                 b_proj, x, out, nullptr);
    ln_k<<<16384, 256, 0, stream>>>(out, ln2_g, ln2_b, hbuf);
    gemm_bt<EPI_RELU><<<2048, 512, 0, stream>>>(hbuf, w1T, 512, 2048, 8,
                                                b1, nullptr, nullptr, ff);
    gemm_bt<EPI_RESF32><<<512, 512, 0, stream>>>(ff, w2T, 2048, 512, 2,
                                                 b2, out, out, nullptr);
  }
}

// Round 18
// 779.033 us; speedup vs baseline: 1.0235x; 1.0235x over previous
//
#include <hip/hip_runtime.h>
#include <hip/hip_bf16.h>

typedef __attribute__((ext_vector_type(8))) short s16x8;
typedef __attribute__((ext_vector_type(4))) short s16x4;
typedef __attribute__((ext_vector_type(4))) float f32x4;

#define GAS __attribute__((address_space(1)))
#define LAS __attribute__((address_space(3)))

#define WAITV(N) asm volatile("s_waitcnt vmcnt(" #N ")" ::: "memory")
#define WAITL() asm volatile("s_waitcnt lgkmcnt(0)" ::: "memory")
#define BAR() __builtin_amdgcn_s_barrier()
#define SCHED0() __builtin_amdgcn_sched_barrier(0)

__device__ __forceinline__ float b2f(unsigned short u) {
  union { unsigned int i; float f; } x; x.i = ((unsigned int)u) << 16; return x.f;
}
__device__ __forceinline__ unsigned short f2b(float f) {
  union { float f; unsigned int i; } x; x.f = f;
  unsigned int r = x.i + 0x7fffu + ((x.i >> 16) & 1u);
  return (unsigned short)(r >> 16);
}

// async global->LDS, 16B per lane; lds dest is wave-uniform base + lane*16
__device__ __forceinline__ void gl16(const unsigned short* g, unsigned short* l) {
  __builtin_amdgcn_global_load_lds((const GAS unsigned int*)g,
                                   (LAS unsigned int*)l, 16, 0, 0);
}

// ---------------- packing ----------------
__global__ __launch_bounds__(256) void pack_qkv_k(const float* __restrict__ wq,
                                                  const float* __restrict__ wk,
                                                  const float* __restrict__ wv,
                                                  unsigned short* __restrict__ dst) {
  int idx = blockIdx.x * 256 + threadIdx.x;   // n*512 + c
  int n = idx >> 9, c = idx & 511;
  int sel = n >> 9;
  int hn = n & 511;
  const float* src = sel == 0 ? wq : (sel == 1 ? wk : wv);
  float v = src[((hn >> 6) << 15) + (c << 6) + (hn & 63)];  // wq[h][c][d]
  dst[idx] = f2b(v);
}

// dst[n][k] = src[k][n], src is (K,N) row-major
__global__ __launch_bounds__(256) void pack_T_k(const float* __restrict__ src,
                                                unsigned short* __restrict__ dst,
                                                int K, int N) {
  int idx = blockIdx.x * 256 + threadIdx.x;
  int n = idx / K, k = idx % K;
  dst[idx] = f2b(src[(long long)k * N + n]);
}

// ---------------- LN1 fused with x->bf16 pack (fp32 input, writes h and xb) ----------------
__global__ __launch_bounds__(256) void ln_fx_k(const float* __restrict__ in,
                                               const float* __restrict__ g,
                                               const float* __restrict__ bb,
                                               unsigned short* __restrict__ out,
                                               unsigned short* __restrict__ xb) {
  int row = blockIdx.x * 4 + (threadIdx.x >> 6);
  int lane = threadIdx.x & 63;
  const float* p = in + (size_t)row * 512 + lane * 8;
  f32x4 a = *(const f32x4*)p;
  f32x4 b = *(const f32x4*)(p + 4);
  float vals[8] = {a.x, a.y, a.z, a.w, b.x, b.y, b.z, b.w};
  s16x8 xo;
#pragma unroll
  for (int i = 0; i < 8; i++) xo[i] = (short)f2b(vals[i]);
  *(s16x8*)(xb + (size_t)row * 512 + lane * 8) = xo;
  float s = 0.f, q = 0.f;
#pragma unroll
  for (int i = 0; i < 8; i++) { s += vals[i]; q += vals[i] * vals[i]; }
#pragma unroll
  for (int off = 1; off < 64; off <<= 1) {
    s += __shfl_xor(s, off);
    q += __shfl_xor(q, off);
  }
  float mean = s * (1.0f / 512.0f);
  float rstd = rsqrtf(q * (1.0f / 512.0f) - mean * mean + 1e-5f);
  const float* gp = g + lane * 8;
  const float* bp = bb + lane * 8;
  s16x8 o;
#pragma unroll
  for (int i = 0; i < 8; i++) o[i] = (short)f2b((vals[i] - mean) * rstd * gp[i] + bp[i]);
  *(s16x8*)(out + (size_t)row * 512 + lane * 8) = o;
}

// ---------------- layernorm (wave per row, C=512), fp32 input (fallback) ----------------
__global__ __launch_bounds__(256) void ln_k(const float* __restrict__ in,
                                            const float* __restrict__ g,
                                            const float* __restrict__ bb,
                                            unsigned short* __restrict__ out) {
  int row = blockIdx.x * 4 + (threadIdx.x >> 6);
  int lane = threadIdx.x & 63;
  const float* p = in + (size_t)row * 512 + lane * 8;
  f32x4 a = *(const f32x4*)p;
  f32x4 b = *(const f32x4*)(p + 4);
  float vals[8] = {a.x, a.y, a.z, a.w, b.x, b.y, b.z, b.w};
  float s = 0.f, q = 0.f;
#pragma unroll
  for (int i = 0; i < 8; i++) { s += vals[i]; q += vals[i] * vals[i]; }
#pragma unroll
  for (int off = 1; off < 64; off <<= 1) {
    s += __shfl_xor(s, off);
    q += __shfl_xor(q, off);
  }
  float mean = s * (1.0f / 512.0f);
  float rstd = rsqrtf(q * (1.0f / 512.0f) - mean * mean + 1e-5f);
  const float* gp = g + lane * 8;
  const float* bp = bb + lane * 8;
  s16x8 o;
#pragma unroll
  for (int i = 0; i < 8; i++) o[i] = (short)f2b((vals[i] - mean) * rstd * gp[i] + bp[i]);
  *(s16x8*)(out + (size_t)row * 512 + lane * 8) = o;
}

// ---------------- layernorm, bf16 input ----------------
__global__ __launch_bounds__(256) void ln_b_k(const unsigned short* __restrict__ in,
                                              const float* __restrict__ g,
                                              const float* __restrict__ bb,
                                              unsigned short* __restrict__ out) {
  int row = blockIdx.x * 4 + (threadIdx.x >> 6);
  int lane = threadIdx.x & 63;
  s16x8 v8 = *(const s16x8*)(in + (size_t)row * 512 + lane * 8);
  float vals[8];
#pragma unroll
  for (int i = 0; i < 8; i++) vals[i] = b2f((unsigned short)v8[i]);
  float s = 0.f, q = 0.f;
#pragma unroll
  for (int i = 0; i < 8; i++) { s += vals[i]; q += vals[i] * vals[i]; }
#pragma unroll
  for (int off = 1; off < 64; off <<= 1) {
    s += __shfl_xor(s, off);
    q += __shfl_xor(q, off);
  }
  float mean = s * (1.0f / 512.0f);
  float rstd = rsqrtf(q * (1.0f / 512.0f) - mean * mean + 1e-5f);
  const float* gp = g + lane * 8;
  const float* bp = bb + lane * 8;
  s16x8 o;
#pragma unroll
  for (int i = 0; i < 8; i++) o[i] = (short)f2b((vals[i] - mean) * rstd * gp[i] + bp[i]);
  *(s16x8*)(out + (size_t)row * 512 + lane * 8) = o;
}

// ---------------- attention (one wave per (b,h); T=16, D=64) ----------------
__global__ __launch_bounds__(256) void attn_k(const unsigned short* __restrict__ qkv,
                                              unsigned short* __restrict__ o) {
  int w = (blockIdx.x << 2) + (threadIdx.x >> 6);
  int lane = threadIdx.x & 63;
  int b = w >> 3, h = w & 7;
  int t = lane >> 2, p = lane & 3;   // 4 lanes per query row, 16 d's each

  size_t rowq = (size_t)(b * 16 + t) * 1536 + h * 64 + p * 16;
  float q[16];
  {
    s16x8 q0 = *(const s16x8*)(qkv + rowq);
    s16x8 q1 = *(const s16x8*)(qkv + rowq + 8);
#pragma unroll
    for (int i = 0; i < 8; i++) {
      q[i] = b2f((unsigned short)q0[i]) * 0.125f;
      q[8 + i] = b2f((unsigned short)q1[i]) * 0.125f;
    }
  }
  float lg[16];
  size_t kbase = (size_t)(b * 16) * 1536 + 512 + h * 64 + p * 16;
#pragma unroll
  for (int s = 0; s < 16; s++) {
    const unsigned short* kp = qkv + kbase + (size_t)s * 1536;
    s16x8 k0 = *(const s16x8*)kp;
    s16x8 k1 = *(const s16x8*)(kp + 8);
    float d = 0.f;
#pragma unroll
    for (int i = 0; i < 8; i++)
      d += q[i] * b2f((unsigned short)k0[i]) + q[8 + i] * b2f((unsigned short)k1[i]);
    d += __shfl_xor(d, 1);
    d += __shfl_xor(d, 2);
    lg[s] = d;
  }
  float mx = -1e30f;
#pragma unroll
  for (int s = 0; s < 16; s++)
    if (s <= t) mx = fmaxf(mx, lg[s]);
  float den = 0.f;
#pragma unroll
  for (int s = 0; s < 16; s++) {
    float e = (s <= t) ? __expf(lg[s] - mx) : 0.f;
    lg[s] = e;
    den += e;
  }
  float inv = 1.f / den;
  float acc[16] = {};
  size_t vbase = kbase + 512;
#pragma unroll
  for (int s = 0; s < 16; s++) {
    const unsigned short* vp = qkv + vbase + (size_t)s * 1536;
    s16x8 v0 = *(const s16x8*)vp;
    s16x8 v1 = *(const s16x8*)(vp + 8);
    float a = lg[s] * inv;
#pragma unroll
    for (int i = 0; i < 8; i++) {
      acc[i] += a * b2f((unsigned short)v0[i]);
      acc[8 + i] += a * b2f((unsigned short)v1[i]);
    }
  }
  size_t orow = (size_t)(b * 16 + t) * 512 + h * 64 + p * 16;
  s16x8 r0, r1;
#pragma unroll
  for (int i = 0; i < 8; i++) {
    r0[i] = (short)f2b(acc[i]);
    r1[i] = (short)f2b(acc[8 + i]);
  }
  *(s16x8*)(o + orow) = r0;
  *(s16x8*)(o + orow + 8) = r1;
}

// ------- bf16 MFMA GEMM: 256x256, BK=32, 8 waves, ring-12, reads-before-barrier -------
// m201-discipline cadence: ds_reads for a phase are ISSUED in the previous phase
// (before the tile barrier) and waited with lgkmcnt(0)+sched_barrier AFTER it --
// LDS latency drains under the barrier/stage window (the lever r11-r17 missed).
// Per tile: 1 s_barrier, 1 counted vmcnt, 2 lgkm waits, 32 MFMA.
//   top:  stage(t+2) x4gl16   [group (t+2)%3 = group t-1: all its reads complete
//                              before tile t-1's barrier -- proven by lgkm waits]
//         WAITL,SCHED0; setprio(1) MFMA m0-3 x16 setprio(0)
//         ds_read A(t) m4-7   [hides under m0-3 MFMAs]
//         WAITL,SCHED0; setprio(1) MFMA m4-7 x16 setprio(0)
//   tail: WAITV(4) [own (t+1) stages landed] ; BAR [=> ALL waves' landed]
//         ds_read B(t+1) + A(t+1) m0-3      [for next tile, latency spans barrier]
// LDS: 12 slots x 8KB = 96KB (group g=t%3: A-half0,A-half1,B-half0,B-half1).
// Source-side XOR swizzle pair (0 conflicts measured r2-r17).
enum { EPI_BF16 = 0, EPI_RESF32 = 1, EPI_RELU = 2, EPI_YBB = 3, EPI_OUTB = 4 };

template <int EPI>
__global__ __launch_bounds__(512) void gemm_bt(
    const unsigned short* __restrict__ A,   // (M, K) bf16
    const unsigned short* __restrict__ Bt,  // (N, K) bf16
    int K, int N, int nT,
    const float* __restrict__ bias, const void* __restrict__ res,
    float* __restrict__ outF, unsigned short* __restrict__ outB) {
  __shared__ __align__(16) unsigned char SM[98304];  // 12 x 8KB

  int tid = threadIdx.x;
  // XCD-chunked 1D swizzle, N-fastest tile order (grids are multiples of 8)
  int lid = ((int)blockIdx.x & 7) * ((int)gridDim.x >> 3) + ((int)blockIdx.x >> 3);
  int mBase = (lid / nT) * 256;
  int nBase = (lid % nT) * 256;

  int lane = tid & 63;
  int wid = tid >> 6;     // 0..7
  int wm = wid >> 2;      // 0..1 -> A half (rows wm*128..)
  int wn = wid & 3;       // 0..3 -> out cols wn*64..
  int l15 = lane & 15;
  int s4 = lane >> 4;
  int lr4 = s4 * 4;
  int fc = ((s4 ^ ((l15 >> 1) & 3)) << 3);   // swizzled 8-elem slot for ds_read

  // staging: thread covers row tid>>2 (0..127) of a half, 16B slot tid&3;
  // source col pre-swizzled: LDS[r][p] = G[r][p ^ ((r>>1)&3)]
  int srow = tid >> 2;
  int scol = (((tid & 3) ^ ((srow >> 1) & 3)) << 3);
  const unsigned short* pa = A + (size_t)(mBase + srow) * K + scol;
  const unsigned short* pb = Bt + (size_t)(nBase + srow) * K + scol;
  size_t k128 = (size_t)128 * K;
  unsigned short* stBase = (unsigned short*)SM + wid * 512;

  f32x4 acc[8][4] = {};

  // group g slots (shorts): A-half a at g*16384 + a*4096; B-half b at g*16384 + 8192 + b*4096
  auto stage4 = [&](int g, int t) {
    unsigned short* d = stBase + g * 16384;
    gl16(pa + t * 32, d);                    // A half0
    gl16(pa + k128 + t * 32, d + 4096);      // A half1
    gl16(pb + t * 32, d + 8192);             // B half0
    gl16(pb + k128 + t * 32, d + 12288);     // B half1
  };

  int NT = K >> 5;   // 16 or 64
  stage4(0, 0);
  stage4(1, 1);
  WAITV(4);          // tile 0's 4 landed (own)
  BAR();             // collective
  s16x8 bf[4], af0[4], af1[4];
  {
    const unsigned short* hB = (const unsigned short*)SM + 8192 + ((wn >> 1) * 4096);
    const unsigned short* hA = (const unsigned short*)SM + wm * 4096;
    int br = (wn & 1) * 64;
#pragma unroll
    for (int n = 0; n < 4; ++n) bf[n] = *(const s16x8*)&hB[(br + n * 16 + l15) * 32 + fc];
#pragma unroll
    for (int m = 0; m < 4; ++m) af0[m] = *(const s16x8*)&hA[(m * 16 + l15) * 32 + fc];
  }

  int g = 0, g1 = 1, g2 = 2;
  for (int t = 0; t < NT; ++t) {
    if (t + 2 < NT) stage4(g2, t + 2);
    WAITL(); SCHED0();                 // bf/af0 ready (latency spanned the barrier)
    __builtin_amdgcn_s_setprio(1);
#pragma unroll
    for (int m = 0; m < 4; ++m)
#pragma unroll
      for (int n = 0; n < 4; ++n)
        acc[m][n] = __builtin_amdgcn_mfma_f32_16x16x32_bf16(af0[m], bf[n], acc[m][n], 0, 0, 0);
    __builtin_amdgcn_s_setprio(0);
    {
      const unsigned short* hA = (const unsigned short*)SM + g * 16384 + wm * 4096;
#pragma unroll
      for (int m = 0; m < 4; ++m)
        af1[m] = *(const s16x8*)&hA[((m + 4) * 16 + l15) * 32 + fc];
    }
    WAITL(); SCHED0();                 // af1 ready (hid under m0-3 MFMAs)
    __builtin_amdgcn_s_setprio(1);
#pragma unroll
    for (int m = 0; m < 4; ++m)
#pragma unroll
      for (int n = 0; n < 4; ++n)
        acc[m + 4][n] = __builtin_amdgcn_mfma_f32_16x16x32_bf16(af1[m], bf[n], acc[m + 4][n], 0, 0, 0);
    __builtin_amdgcn_s_setprio(0);

    if (t + 1 < NT) {
      if (t + 2 < NT) { WAITV(4); } else { WAITV(0); }   // own (t+1) stages landed
      BAR();                                             // all waves' landed; tile-t reads done
      const unsigned short* hB = (const unsigned short*)SM + g1 * 16384 + 8192 + ((wn >> 1) * 4096);
      const unsigned short* hA = (const unsigned short*)SM + g1 * 16384 + wm * 4096;
      int br = (wn & 1) * 64;
#pragma unroll
      for (int n = 0; n < 4; ++n) bf[n] = *(const s16x8*)&hB[(br + n * 16 + l15) * 32 + fc];
#pragma unroll
      for (int m = 0; m < 4; ++m) af0[m] = *(const s16x8*)&hA[(m * 16 + l15) * 32 + fc];
    }
    int tmp = g; g = g1; g1 = g2; g2 = tmp;
  }
  BAR();             // safe to reuse LDS for epilogue staging

  if (EPI == EPI_RESF32 || EPI == EPI_OUTB) {
    // fp32 output: direct stores are full 64B lines
#pragma unroll
    for (int n = 0; n < 4; n++) {
      int gc2 = nBase + wn * 64 + n * 16 + l15;
      float bv = bias[gc2];
#pragma unroll
      for (int m = 0; m < 8; m++) {
#pragma unroll
        for (int j = 0; j < 4; j++) {
          int gr = mBase + wm * 128 + m * 16 + lr4 + j;
          size_t off = (size_t)gr * N + gc2;
          float v = acc[m][n][j] + bv;
          if (EPI == EPI_RESF32)
            outF[off] = v + ((const float*)res)[off];
          else
            outF[off] = v + b2f(((const unsigned short*)res)[off]);
        }
      }
    }
  } else {
    // bf16 output: stage per-wave 16x64 fp32 in LDS, read back row-contiguous,
    // write short4 (16 lanes x 8B = 128B full-line runs per row)
    float* ep = (float*)SM + wid * 1088;   // 4352 B/wave, row stride 68 floats
    int colc = nBase + wn * 64 + l15 * 4;
    f32x4 bias4 = {0.f, 0.f, 0.f, 0.f};
    if (EPI != EPI_BF16) bias4 = *(const f32x4*)&bias[colc];
#pragma unroll
    for (int m = 0; m < 8; m++) {
#pragma unroll
      for (int n = 0; n < 4; n++)
#pragma unroll
        for (int j = 0; j < 4; j++)
          ep[(lr4 + j) * 68 + n * 16 + l15] = acc[m][n][j];
      WAITL();
#pragma unroll
      for (int rd = 0; rd < 4; rd++) {
        int r = s4 + 4 * rd;
        f32x4 v = *(const f32x4*)&ep[r * 68 + l15 * 4];
        v.x += bias4.x; v.y += bias4.y; v.z += bias4.z; v.w += bias4.w;
        int gr = mBase + wm * 128 + m * 16 + r;
        size_t off = (size_t)gr * N + colc;
        if (EPI == EPI_YBB) {
          s16x4 rb = *(const s16x4*)((const unsigned short*)res + off);
          v.x += b2f((unsigned short)rb[0]); v.y += b2f((unsigned short)rb[1]);
          v.z += b2f((unsigned short)rb[2]); v.w += b2f((unsigned short)rb[3]);
        } else if (EPI == EPI_RELU) {
          v.x = fmaxf(v.x, 0.f); v.y = fmaxf(v.y, 0.f);
          v.z = fmaxf(v.z, 0.f); v.w = fmaxf(v.w, 0.f);
        }
        s16x4 o;
        o[0] = (short)f2b(v.x); o[1] = (short)f2b(v.y);
        o[2] = (short)f2b(v.z); o[3] = (short)f2b(v.w);
        *(s16x4*)(outB + off) = o;
      }
      WAITL();  // reads of m done before m+1 overwrites (per-wave region)
    }
  }
}

// ---------------- launch ----------------
extern "C" void kernel_launch(void* const* d_in, const int* in_sizes, int n_in,
                              void* d_out, int out_size, void* d_ws, size_t ws_size,
                              hipStream_t stream) {
  const float* x      = (const float*)d_in[0];
  const float* ln1_g  = (const float*)d_in[1];
  const float* ln1_b  = (const float*)d_in[2];
  const float* wq     = (const float*)d_in[3];
  const float* wk     = (const float*)d_in[4];
  const float* wv     = (const float*)d_in[5];
  const float* w_proj = (const float*)d_in[6];
  const float* b_proj = (const float*)d_in[7];
  const float* ln2_g  = (const float*)d_in[8];
  const float* ln2_b  = (const float*)d_in[9];
  const float* w1     = (const float*)d_in[10];
  const float* b1     = (const float*)d_in[11];
  const float* w2     = (const float*)d_in[12];
  const float* b2     = (const float*)d_in[13];
  float* out = (float*)d_out;

  char* ws = (char*)d_ws;
  unsigned short* qkvT  = (unsigned short*)(ws + 0);          // 1.5 MB
  unsigned short* projT = (unsigned short*)(ws + 1572864);    // 0.5 MB
  unsigned short* w1T   = (unsigned short*)(ws + 2097152);    // 2 MB
  unsigned short* w2T   = (unsigned short*)(ws + 4194304);    // 2 MB
  unsigned short* hbuf  = (unsigned short*)(ws + 6291456);    // 67 MB (h, then h2)
  unsigned short* qkv   = (unsigned short*)(ws + 73400320);   // 201 MB of 268 MB region (ff)
  unsigned short* xb    = (unsigned short*)(ws + 274726912);  // 67 MB spare in ff region
  unsigned short* obuf  = (unsigned short*)(ws + 341835776);  // 67 MB
  unsigned short* ybuf  = (unsigned short*)(ws + 408944640);  // 67 MB (bf16 y) if room
  bool yb16 = ws_size >= 476053504ull;

  pack_qkv_k<<<3072, 256, 0, stream>>>(wq, wk, wv, qkvT);
  pack_T_k<<<1024, 256, 0, stream>>>(w_proj, projT, 512, 512);
  pack_T_k<<<4096, 256, 0, stream>>>(w1, w1T, 512, 2048);
  pack_T_k<<<4096, 256, 0, stream>>>(w2, w2T, 2048, 512);

  unsigned short* ff = qkv;  // ff (268 MB) overlays qkv+xb after both are dead
  if (yb16) {
    // LN1 fused with x->bf16 pack (reads x once)
    ln_fx_k<<<16384, 256, 0, stream>>>(x, ln1_g, ln1_b, hbuf, xb);
    // qkv = h @ [wq|wk|wv]  (M=65536, K=512, N=1536): 256 m x 6 n = 1536
    gemm_bt<EPI_BF16><<<1536, 512, 0, stream>>>(hbuf, qkvT, 512, 1536, 6,
                                                nullptr, nullptr, nullptr, qkv);
    attn_k<<<8192, 256, 0, stream>>>(qkv, obuf);
    // y(bf16) = o @ w_proj + b_proj + xb
    gemm_bt<EPI_YBB><<<512, 512, 0, stream>>>(obuf, projT, 512, 512, 2,
                                              b_proj, xb, nullptr, ybuf);
    ln_b_k<<<16384, 256, 0, stream>>>(ybuf, ln2_g, ln2_b, hbuf);
    // ff = relu(h2 @ w1 + b1)  — overwrites qkv AND xb region (both dead)
    gemm_bt<EPI_RELU><<<2048, 512, 0, stream>>>(hbuf, w1T, 512, 2048, 8,
                                                b1, nullptr, nullptr, ff);
    // out(f32) = ff @ w2 + b2 + y(bf16)
    gemm_bt<EPI_OUTB><<<512, 512, 0, stream>>>(ff, w2T, 2048, 512, 2,
                                               b2, ybuf, out, nullptr);
  } else {
    // fallback: y fp32 in d_out, no xb
    ln_k<<<16384, 256, 0, stream>>>(x, ln1_g, ln1_b, hbuf);
    gemm_bt<EPI_BF16><<<1536, 512, 0, stream>>>(hbuf, qkvT, 512, 1536, 6,
                                                nullptr, nullptr, nullptr, qkv);
    attn_k<<<8192, 256, 0, stream>>>(qkv, obuf);
    gemm_bt<EPI_RESF32><<<512, 512, 0, stream>>>(obuf, projT, 512, 512, 2,
                                                 b_proj, x, out, nullptr);
    ln_k<<<16384, 256, 0, stream>>>(out, ln2_g, ln2_b, hbuf);
    gemm_bt<EPI_RELU><<<2048, 512, 0, stream>>>(hbuf, w1T, 512, 2048, 8,
                                                b1, nullptr, nullptr, ff);
    gemm_bt<EPI_RESF32><<<512, 512, 0, stream>>>(ff, w2T, 2048, 512, 2,
                                                 b2, out, out, nullptr);
  }
}